// Round 4
// baseline (548.683 us; speedup 1.0000x reference)
//
#include <hip/hip_runtime.h>

// QuantLinearBase: out = fakequant_i8(x) @ dequant_i4(W).T + bias
// Exact integer GEMM on the i8 MFMA pipe:
//   out[m,n] = (s * ws) * sum_k qx[m,k]*qw[n,k] + bias[n]
// qx = round(x/s) int8, qw in [-8,7] int8, s = amax/127. int32 accum exact.
//
// GEMM v4: 256x256 block tile, FOUR waves (2x2), wave tile 128x128 ->
// reads/MFMA drops 0.375 -> 0.25 so the LDS read pipe (1024 cyc/tile/CU)
// now fits under the MFMA window (1306 cyc/tile/CU). 1 wave/SIMD, 512-VGPR
// budget holds the 256-reg accumulator + pipelined fragments. 4-deep LDS
// tile ring, counted vmcnt (12/8/0), XOR swizzle (conflicts measured 0),
// fragment pipelining (every MFMA consumes regs read one cluster earlier),
// one barrier per K-tile.

typedef __attribute__((ext_vector_type(4))) int int32x4;

__device__ __forceinline__ void async_copy16(const void* gsrc, void* ldsdst) {
  __builtin_amdgcn_global_load_lds(
      (const __attribute__((address_space(1))) void*)gsrc,
      (__attribute__((address_space(3))) void*)ldsdst, 16, 0, 0);
}

// ---------------- Pass 1: per-block partial amax(|x|) ----------------
__global__ void amax_kernel(const float* __restrict__ x,
                            float* __restrict__ partial, int n4) {
  int tid = blockIdx.x * blockDim.x + threadIdx.x;
  int stride = gridDim.x * blockDim.x;
  float m = 0.0f;
  const float4* x4 = (const float4*)x;
  for (int i = tid; i < n4; i += 2 * stride) {
    float4 v = x4[i];
    float4 w = (i + stride < n4) ? x4[i + stride]
                                 : make_float4(0.f, 0.f, 0.f, 0.f);
    m = fmaxf(m, fmaxf(fmaxf(fabsf(v.x), fabsf(v.y)),
                       fmaxf(fabsf(v.z), fabsf(v.w))));
    m = fmaxf(m, fmaxf(fmaxf(fabsf(w.x), fabsf(w.y)),
                       fmaxf(fabsf(w.z), fabsf(w.w))));
  }
#pragma unroll
  for (int off = 32; off > 0; off >>= 1)
    m = fmaxf(m, __shfl_down(m, off, 64));
  __shared__ float red[4];
  if ((threadIdx.x & 63) == 0) red[threadIdx.x >> 6] = m;
  __syncthreads();
  if (threadIdx.x == 0) {
    partial[blockIdx.x] = fmaxf(fmaxf(red[0], red[1]), fmaxf(red[2], red[3]));
  }
}

// ---------------- Pass 2: quantize x -> int8 (amax reduce folded in) ----
// Every block redundantly reduces the 1024 partials (4 KB, L2-hit) -> no
// separate 1-block reduce launch. Block 0 publishes the scalar for gemm.
__global__ void quant_kernel(const float* __restrict__ x,
                             const float* __restrict__ partial,
                             float* __restrict__ amax_out,
                             unsigned* __restrict__ qx, int n4) {
  const int t = threadIdx.x;  // 256 threads
  float m = fmaxf(fmaxf(partial[t], partial[t + 256]),
                  fmaxf(partial[t + 512], partial[t + 768]));
#pragma unroll
  for (int off = 32; off > 0; off >>= 1)
    m = fmaxf(m, __shfl_down(m, off, 64));
  __shared__ float red[4];
  if ((t & 63) == 0) red[t >> 6] = m;
  __syncthreads();
  __shared__ float s_bcast;
  if (t == 0) {
    float amax = fmaxf(fmaxf(red[0], red[1]), fmaxf(red[2], red[3]));
    if (blockIdx.x == 0) *amax_out = amax;
    float s = amax / 127.0f;  // same op as reference
    if (s == 0.0f) s = 1.0f;
    s_bcast = 1.0f / s;
  }
  __syncthreads();
  const float inv = s_bcast;

  int tid = blockIdx.x * blockDim.x + t;
  int stride = gridDim.x * blockDim.x;
  const float4* x4 = (const float4*)x;
  for (int i = tid; i < n4; i += stride) {
    float4 v = x4[i];
    int a = __float2int_rn(v.x * inv);  // RNE, matches jnp.round
    int b = __float2int_rn(v.y * inv);
    int c = __float2int_rn(v.z * inv);
    int d = __float2int_rn(v.w * inv);
    qx[i] = (unsigned)(a & 0xFF) | ((unsigned)(b & 0xFF) << 8) |
            ((unsigned)(c & 0xFF) << 16) | ((unsigned)(d & 0xFF) << 24);
  }
}

// ---------------- Pass 3: unpack int4 weights -> int8 [O,I] ----------------
__device__ __forceinline__ unsigned pack2(int q) {
  // byte0 (even col) = high nibble - 8, byte1 (odd col) = low nibble - 8
  unsigned hi = (unsigned)((((q >> 4) & 15) - 8) & 0xFF);
  unsigned lo = (unsigned)(((q & 15) - 8) & 0xFF);
  return hi | (lo << 8);
}

__global__ void repack_kernel(const int* __restrict__ qw,
                              uint2* __restrict__ w8, int n4) {
  int tid = blockIdx.x * blockDim.x + threadIdx.x;
  int stride = gridDim.x * blockDim.x;
  const int4* q4 = (const int4*)qw;
  for (int i = tid; i < n4; i += stride) {
    int4 q = q4[i];
    uint2 r;
    r.x = pack2(q.x) | (pack2(q.y) << 16);
    r.y = pack2(q.z) | (pack2(q.w) << 16);
    w8[i] = r;
  }
}

// ---------------- Pass 4: i8 MFMA GEMM, C = A[M,K] @ Bt[N,K]^T ----------
#define BM 256
#define BN 256
#define BKT 64             // K bytes per tile (one 16x16x64 K-slab)
#define TILE_B (BM * BKT)  // 16 KB per operand per tile

// One K-tile, fragment-pipelined, wave tile 128x128.
// CUR_AL (4 frags, M-half 0) and CUR_BF (8 frags) were read during the
// previous tile; afH (M-half 1) is read at phase-A start and consumed in
// phase B. 8 stage-loads per thread per tile (4 in each phase).
// Assumes NT >= 4 and NT even (here K=4096 -> NT=64).
#define TILE_BODY(t, CUR_AL, CUR_BF, NXT_AL, NXT_BF)                          \
  {                                                                           \
    const char* Ab = &As[((t) & 3) * TILE_B];                                 \
    /* ---- phase A: read afH(t) (consumed in phase B), stage, MFMA ---- */   \
    _Pragma("unroll") for (int i = 0; i < 4; ++i) afH[i] =                    \
        *(const int32x4*)(Ab + (arow0 + 64 + i * 16) * BKT + xsl);            \
    if ((t) + 3 < NT) {                                                       \
      const char* sa = aS + ((t) + 3) * BKT;                                  \
      char* ad = aD + (((t) + 3) & 3) * TILE_B;                               \
      async_copy16(sa, ad);                                                   \
      async_copy16(sa + skip1, ad + 4096);                                    \
      async_copy16(sa + skip2, ad + 8192);                                    \
      async_copy16(sa + skip3, ad + 12288);                                   \
    }                                                                         \
    /* CUR frags (12 reads, issued last tile) done; afH's 4 in flight */      \
    asm volatile("s_waitcnt lgkmcnt(4)" ::: "memory");                        \
    __builtin_amdgcn_s_setprio(1);                                            \
    _Pragma("unroll") for (int i = 0; i < 4; ++i)                             \
        _Pragma("unroll") for (int j = 0; j < 8; ++j) acc[i][j] =             \
            __builtin_amdgcn_mfma_i32_16x16x64_i8(CUR_AL[i], CUR_BF[j],       \
                                                  acc[i][j], 0, 0, 0);        \
    __builtin_amdgcn_s_setprio(0);                                            \
    /* ---- phase B: boundary, read tile t+1 frags, stage, MFMA ---- */       \
    if ((t) + 1 < NT) {                                                       \
      asm volatile("s_waitcnt lgkmcnt(0)" ::: "memory");                      \
      /* allowed outstanding: A(t+2)4 + B(t+2)4 + A(t+3)4 = 12 */             \
      if ((t) + 4 <= NT)                                                      \
        asm volatile("s_waitcnt vmcnt(12)" ::: "memory");                     \
      else if ((t) + 3 <= NT)                                                 \
        asm volatile("s_waitcnt vmcnt(8)" ::: "memory");                      \
      else                                                                    \
        asm volatile("s_waitcnt vmcnt(0)" ::: "memory");                      \
      __builtin_amdgcn_s_barrier();                                           \
      __builtin_amdgcn_sched_barrier(0); /* no read hoists above barrier */   \
      const char* Abn = &As[(((t) + 1) & 3) * TILE_B];                        \
      const char* Bbn = &Bs[(((t) + 1) & 3) * TILE_B];                        \
      _Pragma("unroll") for (int i = 0; i < 4; ++i) NXT_AL[i] =               \
          *(const int32x4*)(Abn + (arow0 + i * 16) * BKT + xsl);              \
      _Pragma("unroll") for (int j = 0; j < 8; ++j) NXT_BF[j] =               \
          *(const int32x4*)(Bbn + (brow0 + j * 16) * BKT + xsl);              \
    }                                                                         \
    if ((t) + 3 < NT) {                                                       \
      const char* sb = bS + ((t) + 3) * BKT;                                  \
      char* bd = bD + (((t) + 3) & 3) * TILE_B;                               \
      async_copy16(sb, bd);                                                   \
      async_copy16(sb + skip1, bd + 4096);                                    \
      async_copy16(sb + skip2, bd + 8192);                                    \
      async_copy16(sb + skip3, bd + 12288);                                   \
    }                                                                         \
    __builtin_amdgcn_s_setprio(1);                                            \
    _Pragma("unroll") for (int i = 0; i < 4; ++i)                             \
        _Pragma("unroll") for (int j = 0; j < 8; ++j) acc[4 + i][j] =         \
            __builtin_amdgcn_mfma_i32_16x16x64_i8(afH[i], CUR_BF[j],          \
                                                  acc[4 + i][j], 0, 0, 0);    \
    __builtin_amdgcn_s_setprio(0);                                            \
  }

__global__ __launch_bounds__(256, 1) void gemm_i8(
    const char* __restrict__ A, const char* __restrict__ Bt,
    const float* __restrict__ bias, const float* __restrict__ amax_p,
    const float* __restrict__ wscale, float* __restrict__ C,
    int M, int N, int K) {
  // 4-deep tile ring: 4 x 16 KB per operand = 128 KB total
  __shared__ alignas(16) char As[4 * TILE_B];
  __shared__ alignas(16) char Bs[4 * TILE_B];

  const int tid = threadIdx.x;
  const int lane = tid & 63;
  const int wave = tid >> 6;
  const int wm = wave >> 1;  // 0..1  (128 rows each)
  const int wn = wave & 1;   // 0..1  (128 cols each)
  const int quad = lane >> 4;
  const int l16 = lane & 15;

  // XCD-aware bijective swizzle (nwg = 512, divisible by 8)
  const int cpx = gridDim.x >> 3;
  const int wg = (blockIdx.x & 7) * cpx + (blockIdx.x >> 3);
  const int bM = (wg >> 4) * BM;  // N/BN = 16 n-blocks
  const int bN = (wg & 15) * BN;

  const int NT = K >> 6;  // 64 tiles

  // ---- staging: 256 threads cover 64 rows x 4 slots; 4 row-groups per
  // operand per tile (+0,+64,+128,+192). LDS dest is linear
  // (global_load_lds constraint); the XOR swizzle slot ^= (row>>1)&3 is
  // applied to the GLOBAL source column. Row-group offsets are multiples
  // of 64 rows so the swizzle key (row>>1)&3 is identical across groups.
  const int srow = tid >> 2;  // 0..63
  const int scoff = (((tid & 3) ^ ((tid >> 3) & 3)) << 4);
  const char* aS = A + (size_t)(bM + srow) * K + scoff;
  const char* bS = Bt + (size_t)(bN + srow) * K + scoff;
  const size_t skip1 = (size_t)64 * K;
  const size_t skip2 = (size_t)128 * K;
  const size_t skip3 = (size_t)192 * K;
  char* aD = &As[tid * 16];
  char* bD = &Bs[tid * 16];

  // ---- prologue: stage tiles 0,1,2 (24 global_load_lds per thread)
  for (int tt = 0; tt < 3; ++tt) {
    const int boff = tt * TILE_B;
    const char* sa = aS + tt * BKT;
    const char* sb = bS + tt * BKT;
    async_copy16(sa, aD + boff);
    async_copy16(sa + skip1, aD + boff + 4096);
    async_copy16(sa + skip2, aD + boff + 8192);
    async_copy16(sa + skip3, aD + boff + 12288);
    async_copy16(sb, bD + boff);
    async_copy16(sb + skip1, bD + boff + 4096);
    async_copy16(sb + skip2, bD + boff + 8192);
    async_copy16(sb + skip3, bD + boff + 12288);
  }

  // ---- fragment read constants (swizzled ds_read address).
  const int xsl = ((quad ^ ((l16 >> 1) & 3)) << 4);
  const int arow0 = (wm << 7) + l16;
  const int brow0 = (wn << 7) + l16;

  int32x4 acc[8][8] = {};
  int32x4 afL0[4], afL1[4], afH[4];
  int32x4 bf0[8], bf1[8];

  // tile 0 landed (24 issued; newest 16 = tiles 1,2); then all waves' loads
  asm volatile("s_waitcnt vmcnt(16)" ::: "memory");
  __builtin_amdgcn_s_barrier();
  __builtin_amdgcn_sched_barrier(0);

  // initial fragments for tile 0 phase A (12 reads; order matches loop)
#pragma unroll
  for (int i = 0; i < 4; ++i)
    afL0[i] = *(const int32x4*)(&As[0] + (arow0 + i * 16) * BKT + xsl);
#pragma unroll
  for (int j = 0; j < 8; ++j)
    bf0[j] = *(const int32x4*)(&Bs[0] + (brow0 + j * 16) * BKT + xsl);

  for (int t = 0; t < NT; t += 2) {
    TILE_BODY(t, afL0, bf0, afL1, bf1);
    TILE_BODY(t + 1, afL1, bf1, afL0, bf0);
  }

  // ---- epilogue: scale + bias (C/D layout: col = lane&15, row = quad*4+r)
  float s = *amax_p / 127.0f;
  if (s == 0.0f) s = 1.0f;
  const float cs = s * wscale[0];

#pragma unroll
  for (int fi = 0; fi < 8; ++fi) {
#pragma unroll
    for (int fj = 0; fj < 8; ++fj) {
      const int n = bN + (wn << 7) + fj * 16 + l16;
#pragma unroll
      for (int r = 0; r < 4; ++r) {
        const int m = bM + (wm << 7) + fi * 16 + quad * 4 + r;
        C[(size_t)m * N + n] = (float)acc[fi][fj][r] * cs + bias[n];
      }
    }
  }
}

extern "C" void kernel_launch(void* const* d_in, const int* in_sizes, int n_in,
                              void* d_out, int out_size, void* d_ws,
                              size_t ws_size, hipStream_t stream) {
  const float* x = (const float*)d_in[0];
  const int* qw = (const int*)d_in[1];
  const float* wscale = (const float*)d_in[2];
  const float* bias = (const float*)d_in[3];
  float* out = (float*)d_out;

  const int nx = in_sizes[0];       // B*S*I = 33,554,432
  const int npacked = in_sizes[1];  // O * I/2 = 8,388,608
  const int O = in_sizes[3];        // 4096
  const int I = (npacked / O) * 2;  // 4096
  const int M = nx / I;             // 8192

  float* amax = (float*)d_ws;                    // 4 B
  float* partial = (float*)((char*)d_ws + 256);  // 1024 * 4 B
  char* qx = (char*)d_ws + 8192;
  char* w8 = qx + (size_t)nx;

  // partial[] and *amax are fully overwritten every run; no memset needed
  amax_kernel<<<1024, 256, 0, stream>>>(x, partial, nx / 4);
  quant_kernel<<<2048, 256, 0, stream>>>(x, partial, amax, (unsigned*)qx,
                                         nx / 4);
  repack_kernel<<<1024, 256, 0, stream>>>(qw, (uint2*)w8, npacked / 4);

  const int nwg = (M / BM) * (O / BN);  // 32 * 16 = 512
  gemm_i8<<<nwg, 256, 0, stream>>>(qx, w8, bias, amax, wscale, out, M, O, I);
}

// Round 5
// 430.306 us; speedup vs baseline: 1.2751x; 1.2751x over previous
//
#include <hip/hip_runtime.h>

// QuantLinearBase: out = fakequant_i8(x) @ dequant_i4(W).T + bias
// Exact integer GEMM on the i8 MFMA pipe:
//   out[m,n] = (s * ws) * sum_k qx[m,k]*qw[n,k] + bias[n]
// qx = round(x/s) int8, qw in [-8,7] int8, s = amax/127. int32 accum exact.
//
// GEMM v5 (m201-style 4-phase/K-tile port, i8):
//   256x256 block, 8 waves (2Mx4N), wave tile 128x64, acc[8][4] (128 regs).
//   3-slot LDS ring (96 KB), stage(t+2) spread over P0/P1 (2-tile lead).
//   Per phase: {2 ds_read for NEXT phase; maybe stage; bar; setprio;
//   8 MFMA on frags read LAST phase; setprio; bar}. P3 reads next tile's
//   afL01+bf (6 reads). One counted vmcnt(4)/tile before P2's closing
//   barrier + sched_barrier(0) fences P3's next-slot reads. lgkm waits are
//   compiler-inserted from dataflow (counted, verified behavior per m97).

typedef __attribute__((ext_vector_type(4))) int int32x4;

__device__ __forceinline__ void async_copy16(const void* gsrc, void* ldsdst) {
  __builtin_amdgcn_global_load_lds(
      (const __attribute__((address_space(1))) void*)gsrc,
      (__attribute__((address_space(3))) void*)ldsdst, 16, 0, 0);
}

// ---------------- Pass 1: per-block partial amax(|x|) ----------------
__global__ void amax_kernel(const float* __restrict__ x,
                            float* __restrict__ partial, int n4) {
  int tid = blockIdx.x * blockDim.x + threadIdx.x;
  int stride = gridDim.x * blockDim.x;
  float m = 0.0f;
  const float4* x4 = (const float4*)x;
  for (int i = tid; i < n4; i += 2 * stride) {
    float4 v = x4[i];
    float4 w = (i + stride < n4) ? x4[i + stride]
                                 : make_float4(0.f, 0.f, 0.f, 0.f);
    m = fmaxf(m, fmaxf(fmaxf(fabsf(v.x), fabsf(v.y)),
                       fmaxf(fabsf(v.z), fabsf(v.w))));
    m = fmaxf(m, fmaxf(fmaxf(fabsf(w.x), fabsf(w.y)),
                       fmaxf(fabsf(w.z), fabsf(w.w))));
  }
#pragma unroll
  for (int off = 32; off > 0; off >>= 1)
    m = fmaxf(m, __shfl_down(m, off, 64));
  __shared__ float red[4];
  if ((threadIdx.x & 63) == 0) red[threadIdx.x >> 6] = m;
  __syncthreads();
  if (threadIdx.x == 0) {
    partial[blockIdx.x] = fmaxf(fmaxf(red[0], red[1]), fmaxf(red[2], red[3]));
  }
}

// ---------------- Pass 2: quantize x -> int8 (amax reduce folded in) ----
__global__ void quant_kernel(const float* __restrict__ x,
                             const float* __restrict__ partial,
                             float* __restrict__ amax_out,
                             unsigned* __restrict__ qx, int n4) {
  const int t = threadIdx.x;  // 256 threads
  float m = fmaxf(fmaxf(partial[t], partial[t + 256]),
                  fmaxf(partial[t + 512], partial[t + 768]));
#pragma unroll
  for (int off = 32; off > 0; off >>= 1)
    m = fmaxf(m, __shfl_down(m, off, 64));
  __shared__ float red[4];
  if ((t & 63) == 0) red[t >> 6] = m;
  __syncthreads();
  __shared__ float s_bcast;
  if (t == 0) {
    float amax = fmaxf(fmaxf(red[0], red[1]), fmaxf(red[2], red[3]));
    if (blockIdx.x == 0) *amax_out = amax;
    float s = amax / 127.0f;  // same op as reference
    if (s == 0.0f) s = 1.0f;
    s_bcast = 1.0f / s;
  }
  __syncthreads();
  const float inv = s_bcast;

  int tid = blockIdx.x * blockDim.x + t;
  int stride = gridDim.x * blockDim.x;
  const float4* x4 = (const float4*)x;
  for (int i = tid; i < n4; i += stride) {
    float4 v = x4[i];
    int a = __float2int_rn(v.x * inv);  // RNE, matches jnp.round
    int b = __float2int_rn(v.y * inv);
    int c = __float2int_rn(v.z * inv);
    int d = __float2int_rn(v.w * inv);
    qx[i] = (unsigned)(a & 0xFF) | ((unsigned)(b & 0xFF) << 8) |
            ((unsigned)(c & 0xFF) << 16) | ((unsigned)(d & 0xFF) << 24);
  }
}

// ---------------- Pass 3: unpack int4 weights -> int8 [O,I] ----------------
__device__ __forceinline__ unsigned pack2(int q) {
  // byte0 (even col) = high nibble - 8, byte1 (odd col) = low nibble - 8
  unsigned hi = (unsigned)((((q >> 4) & 15) - 8) & 0xFF);
  unsigned lo = (unsigned)(((q & 15) - 8) & 0xFF);
  return hi | (lo << 8);
}

__global__ void repack_kernel(const int* __restrict__ qw,
                              uint2* __restrict__ w8, int n4) {
  int tid = blockIdx.x * blockDim.x + threadIdx.x;
  int stride = gridDim.x * blockDim.x;
  const int4* q4 = (const int4*)qw;
  for (int i = tid; i < n4; i += stride) {
    int4 q = q4[i];
    uint2 r;
    r.x = pack2(q.x) | (pack2(q.y) << 16);
    r.y = pack2(q.z) | (pack2(q.w) << 16);
    w8[i] = r;
  }
}

// ---------------- Pass 4: i8 MFMA GEMM, C = A[M,K] @ Bt[N,K]^T ----------
#define BM 256
#define BN 256
#define BKT 64             // K bytes per tile (one 16x16x64 K-slab)
#define TILE_B (BM * BKT)  // 16 KB per operand per tile

#define MFMA8(R0, R1, X0, X1, BF)                                          \
  _Pragma("unroll") for (int j = 0; j < 4; ++j) {                          \
    acc[R0][j] = __builtin_amdgcn_mfma_i32_16x16x64_i8(X0, BF[j],          \
                                                       acc[R0][j], 0, 0, 0); \
    acc[R1][j] = __builtin_amdgcn_mfma_i32_16x16x64_i8(X1, BF[j],          \
                                                       acc[R1][j], 0, 0, 0); \
  }

// One K-tile = 4 phases. Entering: pA = afL01(T), BFC = bf(T) (read during
// previous tile's P3). Each phase reads the NEXT phase's A-pair; P3 reads
// tile T+1's afL01 + bf. Staging of tile T+2 split over P0 (A) / P1 (B).
#define TILE4(T, BFC, BFN)                                                    \
  {                                                                           \
    const char* Ab = &As[((T) % 3) * TILE_B];                                 \
    const bool st = (T) + 2 < NT; /* uniform */                               \
    /* ---- P0: read afL23; stage A(T+2); MFMA afL01 x BFC ---- */            \
    pB0 = *(const int32x4*)(Ab + (arow0 + 32) * BKT + xsl);                   \
    pB1 = *(const int32x4*)(Ab + (arow0 + 48) * BKT + xsl);                   \
    if (st) {                                                                 \
      const char* sa = aS + ((T) + 2) * BKT;                                  \
      char* ad = &As[(((T) + 2) % 3) * TILE_B] + tid * 16;                    \
      async_copy16(sa, ad);                                                   \
      async_copy16(sa + skip, ad + 8192);                                     \
    }                                                                         \
    __builtin_amdgcn_s_barrier();                                             \
    __builtin_amdgcn_s_setprio(1);                                            \
    MFMA8(0, 1, pA0, pA1, BFC)                                                \
    __builtin_amdgcn_s_setprio(0);                                            \
    __builtin_amdgcn_s_barrier();                                             \
    /* ---- P1: read afH01; stage B(T+2); MFMA afL23 x BFC ---- */            \
    pA0 = *(const int32x4*)(Ab + (arow0 + 64) * BKT + xsl);                   \
    pA1 = *(const int32x4*)(Ab + (arow0 + 80) * BKT + xsl);                   \
    if (st) {                                                                 \
      const char* sb = bS + ((T) + 2) * BKT;                                  \
      char* bd = &Bs[(((T) + 2) % 3) * TILE_B] + tid * 16;                    \
      async_copy16(sb, bd);                                                   \
      async_copy16(sb + skip, bd + 8192);                                     \
    }                                                                         \
    __builtin_amdgcn_s_barrier();                                             \
    __builtin_amdgcn_s_setprio(1);                                            \
    MFMA8(2, 3, pB0, pB1, BFC)                                                \
    __builtin_amdgcn_s_setprio(0);                                            \
    __builtin_amdgcn_s_barrier();                                             \
    /* ---- P2: read afH23; MFMA afH01 x BFC; vmcnt fence for slot T+1 --- */ \
    pB0 = *(const int32x4*)(Ab + (arow0 + 96) * BKT + xsl);                   \
    pB1 = *(const int32x4*)(Ab + (arow0 + 112) * BKT + xsl);                  \
    __builtin_amdgcn_s_barrier();                                             \
    __builtin_amdgcn_s_setprio(1);                                            \
    MFMA8(4, 5, pA0, pA1, BFC)                                                \
    __builtin_amdgcn_s_setprio(0);                                            \
    /* stage(T+1) (issued during tile T-1) must be landed; outstanding       \
       newest = stage(T+2)'s 4 loads -> counted wait, no drain */             \
    if (st)                                                                   \
      asm volatile("s_waitcnt vmcnt(4)" ::: "memory");                        \
    else                                                                      \
      asm volatile("s_waitcnt vmcnt(0)" ::: "memory");                        \
    __builtin_amdgcn_s_barrier();                                             \
    __builtin_amdgcn_sched_barrier(0); /* P3 reads can't hoist above */       \
    /* ---- P3: read afL01(T+1) + bf(T+1); MFMA afH23 x BFC ---- */           \
    if ((T) + 1 < NT) {                                                       \
      const char* Abn = &As[(((T) + 1) % 3) * TILE_B];                        \
      const char* Bbn = &Bs[(((T) + 1) % 3) * TILE_B];                        \
      pA0 = *(const int32x4*)(Abn + (arow0 + 0) * BKT + xsl);                 \
      pA1 = *(const int32x4*)(Abn + (arow0 + 16) * BKT + xsl);                \
      _Pragma("unroll") for (int j = 0; j < 4; ++j) BFN[j] =                  \
          *(const int32x4*)(Bbn + (brow0 + j * 16) * BKT + xsl);              \
    }                                                                         \
    __builtin_amdgcn_s_barrier();                                             \
    __builtin_amdgcn_s_setprio(1);                                            \
    MFMA8(6, 7, pB0, pB1, BFC)                                                \
    __builtin_amdgcn_s_setprio(0);                                            \
    __builtin_amdgcn_s_barrier();                                             \
  }

__global__ __launch_bounds__(512, 1) void gemm_i8(
    const char* __restrict__ A, const char* __restrict__ Bt,
    const float* __restrict__ bias, const float* __restrict__ amax_p,
    const float* __restrict__ wscale, float* __restrict__ C,
    int M, int N, int K) {
  // 3-slot tile ring: 3 x 16 KB per operand = 96 KB total
  __shared__ alignas(16) char As[3 * TILE_B];
  __shared__ alignas(16) char Bs[3 * TILE_B];

  const int tid = threadIdx.x;
  const int lane = tid & 63;
  const int wave = tid >> 6;
  const int wm = wave >> 2;  // 0..1  (128 rows each)
  const int wn = wave & 3;   // 0..3  (64 cols each)
  const int quad = lane >> 4;
  const int l16 = lane & 15;

  // XCD-aware bijective swizzle (nwg = 512, divisible by 8)
  const int cpx = gridDim.x >> 3;
  const int wg = (blockIdx.x & 7) * cpx + (blockIdx.x >> 3);
  const int bM = (wg >> 4) * BM;  // N/BN = 16 n-blocks
  const int bN = (wg & 15) * BN;

  const int NT = K >> 6;  // 64 tiles (assumes NT >= 4, NT even)

  // ---- staging: 512 threads cover 128 rows x 4 slots per 8 KB issue;
  // two issues (+128 rows) per operand per tile. LDS dest linear
  // (global_load_lds constraint); XOR swizzle slot ^= (row>>1)&3 applied
  // to the GLOBAL source column (128-row offset preserves the key).
  const int srow = tid >> 2;  // 0..127
  const int scoff = (((tid & 3) ^ ((tid >> 3) & 3)) << 4);
  const char* aS = A + (size_t)(bM + srow) * K + scoff;
  const char* bS = Bt + (size_t)(bN + srow) * K + scoff;
  const size_t skip = (size_t)128 * K;

  // ---- prologue: stage tiles 0,1 (A0,B0,A1,B1 order for vmcnt counting)
  for (int tt = 0; tt < 2; ++tt) {
    const int boff = tt * TILE_B;
    const char* sa = aS + tt * BKT;
    const char* sb = bS + tt * BKT;
    async_copy16(sa, &As[boff] + tid * 16);
    async_copy16(sa + skip, &As[boff + 8192] + tid * 16);
    async_copy16(sb, &Bs[boff] + tid * 16);
    async_copy16(sb + skip, &Bs[boff + 8192] + tid * 16);
  }

  // ---- fragment read constants (swizzled ds_read address)
  const int xsl = ((quad ^ ((l16 >> 1) & 3)) << 4);
  const int arow0 = (wm << 7) + l16;
  const int brow0 = (wn << 6) + l16;

  int32x4 acc[8][4] = {};
  int32x4 pA0, pA1, pB0, pB1;
  int32x4 bfA[4], bfB[4];

  // tile 0 landed (8 issued/thread; newest 4 = tile 1's); sync all waves
  asm volatile("s_waitcnt vmcnt(4)" ::: "memory");
  __builtin_amdgcn_s_barrier();
  __builtin_amdgcn_sched_barrier(0);

  // pre-read tile 0's P0 operands: afL01(0) + bf(0)
  pA0 = *(const int32x4*)(&As[0] + (arow0 + 0) * BKT + xsl);
  pA1 = *(const int32x4*)(&As[0] + (arow0 + 16) * BKT + xsl);
#pragma unroll
  for (int j = 0; j < 4; ++j)
    bfA[j] = *(const int32x4*)(&Bs[0] + (brow0 + j * 16) * BKT + xsl);

  for (int t = 0; t < NT; t += 2) {
    TILE4(t, bfA, bfB);
    TILE4(t + 1, bfB, bfA);
  }

  // ---- epilogue: scale + bias (C/D layout: col = lane&15, row = quad*4+r)
  float s = *amax_p / 127.0f;
  if (s == 0.0f) s = 1.0f;
  const float cs = s * wscale[0];

#pragma unroll
  for (int f = 0; f < 8; ++f) {
#pragma unroll
    for (int j = 0; j < 4; ++j) {
      const int n = bN + (wn << 6) + j * 16 + l16;
#pragma unroll
      for (int r = 0; r < 4; ++r) {
        const int m = bM + (wm << 7) + f * 16 + quad * 4 + r;
        C[(size_t)m * N + n] = (float)acc[f][j][r] * cs + bias[n];
      }
    }
  }
}

extern "C" void kernel_launch(void* const* d_in, const int* in_sizes, int n_in,
                              void* d_out, int out_size, void* d_ws,
                              size_t ws_size, hipStream_t stream) {
  const float* x = (const float*)d_in[0];
  const int* qw = (const int*)d_in[1];
  const float* wscale = (const float*)d_in[2];
  const float* bias = (const float*)d_in[3];
  float* out = (float*)d_out;

  const int nx = in_sizes[0];       // B*S*I = 33,554,432
  const int npacked = in_sizes[1];  // O * I/2 = 8,388,608
  const int O = in_sizes[3];        // 4096
  const int I = (npacked / O) * 2;  // 4096
  const int M = nx / I;             // 8192

  float* amax = (float*)d_ws;                    // 4 B
  float* partial = (float*)((char*)d_ws + 256);  // 1024 * 4 B
  char* qx = (char*)d_ws + 8192;
  char* w8 = qx + (size_t)nx;

  // partial[] and *amax are fully overwritten every run; no memset needed
  amax_kernel<<<1024, 256, 0, stream>>>(x, partial, nx / 4);
  quant_kernel<<<2048, 256, 0, stream>>>(x, partial, amax, (unsigned*)qx,
                                         nx / 4);
  repack_kernel<<<1024, 256, 0, stream>>>(qw, (uint2*)w8, npacked / 4);

  const int nwg = (M / BM) * (O / BN);  // 32 * 16 = 512
  gemm_i8<<<nwg, 512, 0, stream>>>(qx, w8, bias, amax, wscale, out, M, O, I);
}

// Round 6
// 411.961 us; speedup vs baseline: 1.3319x; 1.0445x over previous
//
#include <hip/hip_runtime.h>

// QuantLinearBase: out = fakequant_i8(x) @ dequant_i4(W).T + bias
// Exact integer GEMM on the i8 MFMA pipe:
//   out[m,n] = (s * ws) * sum_k qx[m,k]*qw[n,k] + bias[n]
// qx = round(x/s) int8, qw in [-8,7] int8, s = amax/127. int32 accum exact.
//
// GEMM v6 (m201-density 2-phase/K-tile):
//   256x256 block, 8 waves (2Mx4N), wave tile 128x64, acc[8][4].
//   Per phase (m201 discipline): {ds_read this phase's frags; stage issue;
//   s_barrier; lgkmcnt(0)+sched_barrier; setprio(1); 16 MFMA; setprio(0);
//   s_barrier}. 16 MFMA/wave per barrier-pair = m201's proven density
//   (v5's 8-MFMA phases doubled overhead -> 30%; v3's lockstep 1-barrier
//   summed LDS+MFMA -> 39%). vmcnt(4) once per tile (counted, never 0
//   until tail). 3-slot LDS ring (96 KB), XOR swizzle via pre-swizzled
//   global source (bank conflicts measured 0), XCD-aware block swizzle.

typedef __attribute__((ext_vector_type(4))) int int32x4;

__device__ __forceinline__ void async_copy16(const void* gsrc, void* ldsdst) {
  __builtin_amdgcn_global_load_lds(
      (const __attribute__((address_space(1))) void*)gsrc,
      (__attribute__((address_space(3))) void*)ldsdst, 16, 0, 0);
}

// ---------------- Pass 1: per-block partial amax(|x|) ----------------
__global__ void amax_kernel(const float* __restrict__ x,
                            float* __restrict__ partial, int n4) {
  int tid = blockIdx.x * blockDim.x + threadIdx.x;
  int stride = gridDim.x * blockDim.x;
  float m = 0.0f;
  const float4* x4 = (const float4*)x;
  for (int i = tid; i < n4; i += 2 * stride) {
    float4 v = x4[i];
    float4 w = (i + stride < n4) ? x4[i + stride]
                                 : make_float4(0.f, 0.f, 0.f, 0.f);
    m = fmaxf(m, fmaxf(fmaxf(fabsf(v.x), fabsf(v.y)),
                       fmaxf(fabsf(v.z), fabsf(v.w))));
    m = fmaxf(m, fmaxf(fmaxf(fabsf(w.x), fabsf(w.y)),
                       fmaxf(fabsf(w.z), fabsf(w.w))));
  }
#pragma unroll
  for (int off = 32; off > 0; off >>= 1)
    m = fmaxf(m, __shfl_down(m, off, 64));
  __shared__ float red[4];
  if ((threadIdx.x & 63) == 0) red[threadIdx.x >> 6] = m;
  __syncthreads();
  if (threadIdx.x == 0) {
    partial[blockIdx.x] = fmaxf(fmaxf(red[0], red[1]), fmaxf(red[2], red[3]));
  }
}

// ---------------- Pass 2: quantize x -> int8 (amax reduce folded in) ----
__global__ void quant_kernel(const float* __restrict__ x,
                             const float* __restrict__ partial,
                             float* __restrict__ amax_out,
                             unsigned* __restrict__ qx, int n4) {
  const int t = threadIdx.x;  // 256 threads
  float m = fmaxf(fmaxf(partial[t], partial[t + 256]),
                  fmaxf(partial[t + 512], partial[t + 768]));
#pragma unroll
  for (int off = 32; off > 0; off >>= 1)
    m = fmaxf(m, __shfl_down(m, off, 64));
  __shared__ float red[4];
  if ((t & 63) == 0) red[t >> 6] = m;
  __syncthreads();
  __shared__ float s_bcast;
  if (t == 0) {
    float amax = fmaxf(fmaxf(red[0], red[1]), fmaxf(red[2], red[3]));
    if (blockIdx.x == 0) *amax_out = amax;
    float s = amax / 127.0f;  // same op as reference
    if (s == 0.0f) s = 1.0f;
    s_bcast = 1.0f / s;
  }
  __syncthreads();
  const float inv = s_bcast;

  int tid = blockIdx.x * blockDim.x + t;
  int stride = gridDim.x * blockDim.x;
  const float4* x4 = (const float4*)x;
  for (int i = tid; i < n4; i += stride) {
    float4 v = x4[i];
    int a = __float2int_rn(v.x * inv);  // RNE, matches jnp.round
    int b = __float2int_rn(v.y * inv);
    int c = __float2int_rn(v.z * inv);
    int d = __float2int_rn(v.w * inv);
    qx[i] = (unsigned)(a & 0xFF) | ((unsigned)(b & 0xFF) << 8) |
            ((unsigned)(c & 0xFF) << 16) | ((unsigned)(d & 0xFF) << 24);
  }
}

// ---------------- Pass 3: unpack int4 weights -> int8 [O,I] ----------------
__device__ __forceinline__ unsigned pack2(int q) {
  // byte0 (even col) = high nibble - 8, byte1 (odd col) = low nibble - 8
  unsigned hi = (unsigned)((((q >> 4) & 15) - 8) & 0xFF);
  unsigned lo = (unsigned)(((q & 15) - 8) & 0xFF);
  return hi | (lo << 8);
}

__global__ void repack_kernel(const int* __restrict__ qw,
                              uint2* __restrict__ w8, int n4) {
  int tid = blockIdx.x * blockDim.x + threadIdx.x;
  int stride = gridDim.x * blockDim.x;
  const int4* q4 = (const int4*)qw;
  for (int i = tid; i < n4; i += stride) {
    int4 q = q4[i];
    uint2 r;
    r.x = pack2(q.x) | (pack2(q.y) << 16);
    r.y = pack2(q.z) | (pack2(q.w) << 16);
    w8[i] = r;
  }
}

// ---------------- Pass 4: i8 MFMA GEMM, C = A[M,K] @ Bt[N,K]^T ----------
#define BM 256
#define BN 256
#define BKT 64             // K bytes per tile (one 16x16x64 K-slab)
#define TILE_B (BM * BKT)  // 16 KB per operand per tile

__global__ __launch_bounds__(512, 1) void gemm_i8(
    const char* __restrict__ A, const char* __restrict__ Bt,
    const float* __restrict__ bias, const float* __restrict__ amax_p,
    const float* __restrict__ wscale, float* __restrict__ C,
    int M, int N, int K) {
  // 3-slot tile ring: 3 x 16 KB per operand = 96 KB total
  __shared__ alignas(16) char As[3 * TILE_B];
  __shared__ alignas(16) char Bs[3 * TILE_B];

  const int tid = threadIdx.x;
  const int lane = tid & 63;
  const int wave = tid >> 6;
  const int wm = wave >> 2;  // 0..1  (128 rows each)
  const int wn = wave & 3;   // 0..3  (64 cols each)
  const int quad = lane >> 4;
  const int l16 = lane & 15;

  // XCD-aware bijective swizzle (nwg = 512, divisible by 8)
  const int cpx = gridDim.x >> 3;
  const int wg = (blockIdx.x & 7) * cpx + (blockIdx.x >> 3);
  const int bM = (wg >> 4) * BM;  // N/BN = 16 n-blocks
  const int bN = (wg & 15) * BN;

  const int NT = K >> 6;  // 64 tiles (needs NT >= 3)

  // ---- staging: 512 threads cover 128 rows x 4 slots per 8 KB issue;
  // two issues (+128 rows) per operand per tile. LDS dest linear
  // (global_load_lds constraint); XOR swizzle slot ^= (row>>1)&3 applied
  // to the GLOBAL source column (128-row offset preserves the key).
  const int srow = tid >> 2;  // 0..127
  const int scoff = (((tid & 3) ^ ((tid >> 3) & 3)) << 4);
  const char* aS = A + (size_t)(bM + srow) * K + scoff;
  const char* bS = Bt + (size_t)(bN + srow) * K + scoff;
  const size_t skip = (size_t)128 * K;

  // ---- prologue: stage tiles 0,1 in order A0,B0,A1,B1 (8 loads/thread)
  for (int tt = 0; tt < 2; ++tt) {
    const int boff = tt * TILE_B;
    const char* sa = aS + tt * BKT;
    const char* sb = bS + tt * BKT;
    async_copy16(sa, &As[boff] + tid * 16);
    async_copy16(sa + skip, &As[boff + 8192] + tid * 16);
    async_copy16(sb, &Bs[boff] + tid * 16);
    async_copy16(sb + skip, &Bs[boff + 8192] + tid * 16);
  }

  // ---- fragment read constants (swizzled ds_read address)
  const int xsl = ((quad ^ ((l16 >> 1) & 3)) << 4);
  const int arow0 = (wm << 7) + l16;
  const int brow0 = (wn << 6) + l16;

  int32x4 acc[8][4] = {};
  int32x4 af[4], bf[4];

  // tile 0 landed (8 issued/thread; newest 4 = tile 1's A1,B1)
  asm volatile("s_waitcnt vmcnt(4)" ::: "memory");
  __builtin_amdgcn_s_barrier();
  __builtin_amdgcn_sched_barrier(0);

  for (int t = 0; t < NT; ++t) {
    const char* Ab = &As[(t % 3) * TILE_B];
    const char* Bb = &Bs[(t % 3) * TILE_B];
    const bool st = (t + 2 < NT);  // uniform across block

    // ================= P0: afL + bf, stage A(t+2), MFMA low-half =========
#pragma unroll
    for (int i = 0; i < 4; ++i)
      af[i] = *(const int32x4*)(Ab + (arow0 + i * 16) * BKT + xsl);
#pragma unroll
    for (int j = 0; j < 4; ++j)
      bf[j] = *(const int32x4*)(Bb + (brow0 + j * 16) * BKT + xsl);
    if (st) {
      const char* sa = aS + (t + 2) * BKT;
      char* ad = &As[((t + 2) % 3) * TILE_B] + tid * 16;
      async_copy16(sa, ad);
      async_copy16(sa + skip, ad + 8192);
    }
    __builtin_amdgcn_s_barrier();
    asm volatile("s_waitcnt lgkmcnt(0)" ::: "memory");
    __builtin_amdgcn_sched_barrier(0);  // rule #18: MFMA must not hoist
    __builtin_amdgcn_s_setprio(1);
#pragma unroll
    for (int i = 0; i < 4; ++i)
#pragma unroll
      for (int j = 0; j < 4; ++j)
        acc[i][j] = __builtin_amdgcn_mfma_i32_16x16x64_i8(af[i], bf[j],
                                                          acc[i][j], 0, 0, 0);
    __builtin_amdgcn_s_setprio(0);
    __builtin_amdgcn_s_barrier();

    // ================= P1: afH, stage B(t+2), MFMA high-half =============
#pragma unroll
    for (int i = 0; i < 4; ++i)
      af[i] = *(const int32x4*)(Ab + (arow0 + 64 + i * 16) * BKT + xsl);
    if (st) {
      const char* sb = bS + (t + 2) * BKT;
      char* bd = &Bs[((t + 2) % 3) * TILE_B] + tid * 16;
      async_copy16(sb, bd);
      async_copy16(sb + skip, bd + 8192);
    }
    __builtin_amdgcn_s_barrier();
    asm volatile("s_waitcnt lgkmcnt(0)" ::: "memory");
    __builtin_amdgcn_sched_barrier(0);
    __builtin_amdgcn_s_setprio(1);
#pragma unroll
    for (int i = 0; i < 4; ++i)
#pragma unroll
      for (int j = 0; j < 4; ++j)
        acc[4 + i][j] = __builtin_amdgcn_mfma_i32_16x16x64_i8(
            af[i], bf[j], acc[4 + i][j], 0, 0, 0);
    __builtin_amdgcn_s_setprio(0);
    // certify slot t+1 for next tile: outstanding = stage(t+2)'s 4 loads
    if (st)
      asm volatile("s_waitcnt vmcnt(4)" ::: "memory");
    else
      asm volatile("s_waitcnt vmcnt(0)" ::: "memory");
    __builtin_amdgcn_s_barrier();
    __builtin_amdgcn_sched_barrier(0);  // next tile's reads stay below
  }

  // ---- epilogue: scale + bias (C/D layout: col = lane&15, row = quad*4+r)
  float s = *amax_p / 127.0f;
  if (s == 0.0f) s = 1.0f;
  const float cs = s * wscale[0];

#pragma unroll
  for (int f = 0; f < 8; ++f) {
#pragma unroll
    for (int j = 0; j < 4; ++j) {
      const int n = bN + (wn << 6) + j * 16 + l16;
#pragma unroll
      for (int r = 0; r < 4; ++r) {
        const int m = bM + (wm << 7) + f * 16 + quad * 4 + r;
        C[(size_t)m * N + n] = (float)acc[f][j][r] * cs + bias[n];
      }
    }
  }
}

extern "C" void kernel_launch(void* const* d_in, const int* in_sizes, int n_in,
                              void* d_out, int out_size, void* d_ws,
                              size_t ws_size, hipStream_t stream) {
  const float* x = (const float*)d_in[0];
  const int* qw = (const int*)d_in[1];
  const float* wscale = (const float*)d_in[2];
  const float* bias = (const float*)d_in[3];
  float* out = (float*)d_out;

  const int nx = in_sizes[0];       // B*S*I = 33,554,432
  const int npacked = in_sizes[1];  // O * I/2 = 8,388,608
  const int O = in_sizes[3];        // 4096
  const int I = (npacked / O) * 2;  // 4096
  const int M = nx / I;             // 8192

  float* amax = (float*)d_ws;                    // 4 B
  float* partial = (float*)((char*)d_ws + 256);  // 1024 * 4 B
  char* qx = (char*)d_ws + 8192;
  char* w8 = qx + (size_t)nx;

  // partial[] and *amax are fully overwritten every run; no memset needed
  amax_kernel<<<1024, 256, 0, stream>>>(x, partial, nx / 4);
  quant_kernel<<<2048, 256, 0, stream>>>(x, partial, amax, (unsigned*)qx,
                                         nx / 4);
  repack_kernel<<<1024, 256, 0, stream>>>(qw, (uint2*)w8, npacked / 4);

  const int nwg = (M / BM) * (O / BN);  // 32 * 16 = 512
  gemm_i8<<<nwg, 512, 0, stream>>>(qx, w8, bias, amax, wscale, out, M, O, I);
}